// Round 2
// baseline (179.514 us; speedup 1.0000x reference)
//
#include <hip/hip_runtime.h>

#define T_DIM 1024
#define B_DIM 8
#define IN_DIM 1024
#define OUT_DIM 1024
#define N_MODL 16
#define K_SEL 2

typedef unsigned short ushort_t;
typedef __bf16 bf16x8 __attribute__((ext_vector_type(8)));
typedef float f32x4 __attribute__((ext_vector_type(4)));

__device__ __forceinline__ unsigned int f2bf2(float lo, float hi) {
  union { float f; unsigned int u; } a, b; a.f = lo; b.f = hi;
  unsigned int ra = (a.u + 0x7fffu + ((a.u >> 16) & 1u)) >> 16;
  unsigned int rb = (b.u + 0x7fffu + ((b.u >> 16) & 1u)) >> 16;
  return ra | (rb << 16);
}

__device__ __forceinline__ void async_g2l(const void* g, void* l) {
  __builtin_amdgcn_global_load_lds(
      (const __attribute__((address_space(1))) unsigned int*)g,
      (__attribute__((address_space(3))) unsigned int*)l,
      16, 0, 0);
}

__device__ __forceinline__ int read_sel(const int* __restrict__ s, int g) {
  bool i64 = true;
#pragma unroll
  for (int j = 0; j < 8; ++j) i64 &= (s[2 * j + 1] == 0);
  return i64 ? s[2 * g] : s[g];
}

// Blocks [0,1024): W [16,IN,OUT] f32 -> Wt [16,OUT,IN] bf16, 128x128 tiles,
//   bf16-in-LDS with XOR swizzle, skipping experts not present in selection.
// Blocks [1024,5120): x [T,B,IN] f32 -> bf16 stream convert (same layout).
__global__ __launch_bounds__(256) void convert_kernel(const float* __restrict__ x,
                                                      const float* __restrict__ w,
                                                      const int* __restrict__ selp,
                                                      ushort_t* __restrict__ xb,
                                                      ushort_t* __restrict__ wt) {
  __shared__ ushort_t tb[128 * 128];   // 32KB
  const int bid = blockIdx.x;
  if (bid >= 1024) {
    const int i = (bid - 1024) * 256 + threadIdx.x;
    const float4* s = (const float4*)x;
    float4 a = s[i * 2], b = s[i * 2 + 1];
    uint4 o;
    o.x = f2bf2(a.x, a.y); o.y = f2bf2(a.z, a.w);
    o.z = f2bf2(b.x, b.y); o.w = f2bf2(b.z, b.w);
    ((uint4*)xb)[i] = o;
    return;
  }
  const int m = bid >> 6;
  bool used = false;
#pragma unroll
  for (int g = 0; g < B_DIM * K_SEL; ++g) used |= (read_sel(selp, g) == m);
  if (!used) return;

  const int i0 = ((bid >> 3) & 7) * 128;
  const int o0 = (bid & 7) * 128;
  const float* src = w + ((size_t)(m * IN_DIM + i0)) * OUT_DIM + o0;

  const int o4 = (threadIdx.x & 31) * 4;
  const int ib = threadIdx.x >> 5;
#pragma unroll
  for (int p = 0; p < 16; ++p) {
    const int i = ib + p * 8;
    float4 v = *(const float4*)(src + (size_t)i * OUT_DIM + o4);
    const int osw = o4 ^ (((i >> 3) & 15) << 2);
    uint2 d2; d2.x = f2bf2(v.x, v.y); d2.y = f2bf2(v.z, v.w);
    *(uint2*)(tb + i * 128 + osw) = d2;
  }
  __syncthreads();

  ushort_t* dst = wt + ((size_t)(m * OUT_DIM + o0)) * IN_DIM + i0;
  const int il = (threadIdx.x & 15) * 8;
  const int ob = threadIdx.x >> 4;
  const int q2 = ((il >> 3) & 15) << 2;
#pragma unroll
  for (int p = 0; p < 8; ++p) {
    const int o = ob + p * 16;
    const int osw = o ^ q2;
    uint4 d;
    unsigned int u[8];
#pragma unroll
    for (int j = 0; j < 8; ++j) u[j] = tb[(il + j) * 128 + osw];
    d.x = u[0] | (u[1] << 16); d.y = u[2] | (u[3] << 16);
    d.z = u[4] | (u[5] << 16); d.w = u[6] | (u[7] << 16);
    *(uint4*)(dst + (size_t)o * IN_DIM + il) = d;
  }
}

#define MFMA16 __builtin_amdgcn_mfma_f32_16x16x32_bf16

// Fused sibling GEMMs per b (both experts share the A operand). 128x128 tile,
// BK=32, 4 waves x 64x64 x 2 experts, 2 blocks/CU.
// Triple-buffered LDS (72KB): step t stages tile t+2 while computing tile t;
// counted s_waitcnt vmcnt(6) per step (never drained to 0 in the main loop),
// ONE barrier per step. XOR-swizzled LDS:
//   write: lane l -> phys slot l&3 of row (l>>2); logical chunk (l&3)^((l>>3)&3)
//   read : phys chunk = quad ^ ((frow>>1)&3)  -> 2-way bank aliasing (free)
__global__ __launch_bounds__(256, 2) void mlgemm_kernel(const ushort_t* __restrict__ xb,
                                                        const ushort_t* __restrict__ wt,
                                                        const int* __restrict__ selp,
                                                        const float* __restrict__ bias,
                                                        float* __restrict__ out) {
  __shared__ ushort_t As[3][128 * 32];      // 24KB
  __shared__ ushort_t Bs[3][2][128 * 32];   // 48KB

  const int lin = blockIdx.x;
  const int b = lin & 7;                 // XCD = lin % 8 (heuristic)
  const int mtile = (lin >> 3) & 7;
  const int ntile = lin >> 6;
  const int e0 = read_sel(selp, 2 * b);
  const int e1 = read_sel(selp, 2 * b + 1);
  const int m0 = mtile * 128;
  const int n0 = ntile * 128;

  const int tid = threadIdx.x;
  const int lane = tid & 63;
  const int wv = tid >> 6;

  // staging thread mapping: event j = 16 rows x 4 chunks of 16B (1KB/wave-call)
  const int re = lane >> 2;                        // row within event
  const int cl = (lane & 3) ^ ((lane >> 3) & 3);   // logical k-chunk fetched
  const int j0 = wv * 2, j1 = j0 + 1;              // this wave's two events
  const ushort_t* aP0 = xb + (size_t)(m0 + j0 * 16 + re) * (B_DIM * IN_DIM)
                           + b * IN_DIM + cl * 8;
  const ushort_t* aP1 = aP0 + (size_t)16 * (B_DIM * IN_DIM);
  const ushort_t* b0P0 = wt + ((size_t)(e0 * OUT_DIM + n0 + j0 * 16 + re)) * IN_DIM
                            + cl * 8;
  const ushort_t* b0P1 = b0P0 + (size_t)16 * IN_DIM;
  const ushort_t* b1P0 = wt + ((size_t)(e1 * OUT_DIM + n0 + j0 * 16 + re)) * IN_DIM
                            + cl * 8;
  const ushort_t* b1P1 = b1P0 + (size_t)16 * IN_DIM;
  const int jo0 = j0 * 512, jo1 = j1 * 512;        // LDS element offsets (wave-uniform)

  // fragment read mapping
  const int frow = lane & 15;
  const int quad = lane >> 4;
  const int cp = quad ^ ((frow >> 1) & 3);
  const int wrow = (wv & 1) * 64;
  const int wcol = (wv >> 1) * 64;
  const int rdoA = (wrow + frow) * 32 + cp * 8;
  const int rdoB = (wcol + frow) * 32 + cp * 8;

  f32x4 acc0[4][4] = {};
  f32x4 acc1[4][4] = {};

  // prologue: stage tiles 0,1 into buffers 0,1 (12 calls; 6 per tile per wave)
#pragma unroll
  for (int k = 0; k < 2; ++k) {
    const int k0 = k * 32;
    async_g2l(aP0 + k0,  As[k] + jo0);
    async_g2l(aP1 + k0,  As[k] + jo1);
    async_g2l(b0P0 + k0, Bs[k][0] + jo0);
    async_g2l(b0P1 + k0, Bs[k][0] + jo1);
    async_g2l(b1P0 + k0, Bs[k][1] + jo0);
    async_g2l(b1P1 + k0, Bs[k][1] + jo1);
  }
  asm volatile("s_waitcnt vmcnt(6)" ::: "memory");   // tile 0 landed
  __builtin_amdgcn_sched_barrier(0);
  __builtin_amdgcn_s_barrier();
  __builtin_amdgcn_sched_barrier(0);

  // main loop: 32 K-steps, fully unrolled (t%3 static)
#pragma unroll
  for (int t = 0; t < 32; ++t) {
    const int cur = t % 3;
    const int nxt = (t + 2) % 3;
    if (t < 30) {
      const int k0n = (t + 2) * 32;
      async_g2l(aP0 + k0n,  As[nxt] + jo0);
      async_g2l(aP1 + k0n,  As[nxt] + jo1);
      async_g2l(b0P0 + k0n, Bs[nxt][0] + jo0);
      async_g2l(b0P1 + k0n, Bs[nxt][0] + jo1);
      async_g2l(b1P0 + k0n, Bs[nxt][1] + jo0);
      async_g2l(b1P1 + k0n, Bs[nxt][1] + jo1);
      __builtin_amdgcn_sched_barrier(0);
    }
    const ushort_t* Ard  = As[cur] + rdoA;
    const ushort_t* Brd0 = Bs[cur][0] + rdoB;
    const ushort_t* Brd1 = Bs[cur][1] + rdoB;
    bf16x8 af[4], bf0[4], bf1[4];
#pragma unroll
    for (int i = 0; i < 4; ++i) {
      af[i]  = *(const bf16x8*)(Ard  + i * 512);
      bf0[i] = *(const bf16x8*)(Brd0 + i * 512);
      bf1[i] = *(const bf16x8*)(Brd1 + i * 512);
    }
#pragma unroll
    for (int mt = 0; mt < 4; ++mt)
#pragma unroll
      for (int nt = 0; nt < 4; ++nt) {
        acc0[mt][nt] = MFMA16(af[mt], bf0[nt], acc0[mt][nt], 0, 0, 0);
        acc1[mt][nt] = MFMA16(af[mt], bf1[nt], acc1[mt][nt], 0, 0, 0);
      }
    if (t < 29) {
      asm volatile("s_waitcnt vmcnt(6)" ::: "memory");  // tile t+1 landed
    } else if (t < 31) {
      asm volatile("s_waitcnt vmcnt(0)" ::: "memory");  // drain tail
    }
    if (t < 31) {
      __builtin_amdgcn_sched_barrier(0);
      __builtin_amdgcn_s_barrier();
      __builtin_amdgcn_sched_barrier(0);
    }
  }

  // epilogue: C/D map col=lane&15, row=quad*4+reg
  const int orow0 = m0 + wrow + quad * 4;
  const int ocol0 = n0 + wcol + frow;
  const float* bp0 = bias + (size_t)e0 * OUT_DIM;
  const float* bp1 = bias + (size_t)e1 * OUT_DIM;
  float bv0[4], bv1[4];
#pragma unroll
  for (int nt = 0; nt < 4; ++nt) {
    bv0[nt] = bp0[ocol0 + nt * 16];
    bv1[nt] = bp1[ocol0 + nt * 16];
  }
  float* C0 = out + (size_t)b * (K_SEL * OUT_DIM);
  float* C1 = C0 + OUT_DIM;
#pragma unroll
  for (int mt = 0; mt < 4; ++mt) {
#pragma unroll
    for (int r = 0; r < 4; ++r) {
      const size_t rowoff = (size_t)(orow0 + mt * 16 + r) * (B_DIM * K_SEL * OUT_DIM);
#pragma unroll
      for (int nt = 0; nt < 4; ++nt) {
        C0[rowoff + ocol0 + nt * 16] = acc0[mt][nt][r] + bv0[nt];
        C1[rowoff + ocol0 + nt * 16] = acc1[mt][nt][r] + bv1[nt];
      }
    }
  }
}

extern "C" void kernel_launch(void* const* d_in, const int* in_sizes, int n_in,
                              void* d_out, int out_size, void* d_ws, size_t ws_size,
                              hipStream_t stream) {
  const float* x    = (const float*)d_in[0];
  const int*   sel  = (const int*)d_in[1];
  const float* w    = (const float*)d_in[2];
  const float* bias = (const float*)d_in[3];
  float* out = (float*)d_out;

  ushort_t* xb = (ushort_t*)d_ws;                                   // 16 MB
  ushort_t* wt = (ushort_t*)((char*)d_ws +
                             (size_t)T_DIM * B_DIM * IN_DIM * 2);   // +32 MB

  convert_kernel<<<dim3(1024 + T_DIM * B_DIM * IN_DIM / 8 / 256), 256, 0, stream>>>(
      x, w, sel, xb, wt);
  mlgemm_kernel<<<dim3(8 * 8 * B_DIM), 256, 0, stream>>>(xb, wt, sel, bias, out);
}

// Round 3
// 174.793 us; speedup vs baseline: 1.0270x; 1.0270x over previous
//
#include <hip/hip_runtime.h>

#define T_DIM 1024
#define B_DIM 8
#define IN_DIM 1024
#define OUT_DIM 1024
#define N_MODL 16
#define K_SEL 2

typedef unsigned short ushort_t;
typedef __bf16 bf16x8 __attribute__((ext_vector_type(8)));
typedef float f32x4 __attribute__((ext_vector_type(4)));

__device__ __forceinline__ unsigned int f2bf2(float lo, float hi) {
  union { float f; unsigned int u; } a, b; a.f = lo; b.f = hi;
  unsigned int ra = (a.u + 0x7fffu + ((a.u >> 16) & 1u)) >> 16;
  unsigned int rb = (b.u + 0x7fffu + ((b.u >> 16) & 1u)) >> 16;
  return ra | (rb << 16);
}

__device__ __forceinline__ void async_g2l(const void* g, void* l) {
  __builtin_amdgcn_global_load_lds(
      (const __attribute__((address_space(1))) unsigned int*)g,
      (__attribute__((address_space(3))) unsigned int*)l,
      16, 0, 0);
}

__device__ __forceinline__ int read_sel(const int* __restrict__ s, int g) {
  bool i64 = true;
#pragma unroll
  for (int j = 0; j < 8; ++j) i64 &= (s[2 * j + 1] == 0);
  return i64 ? s[2 * g] : s[g];
}

// Blocks [0,1024): W [16,IN,OUT] f32 -> Wt [16,OUT,IN] bf16, 128x128 tiles,
//   bf16-in-LDS with XOR swizzle, skipping experts not present in selection.
// Blocks [1024,5120): x [T,B,IN] f32 -> bf16 stream convert (same layout).
__global__ __launch_bounds__(256) void convert_kernel(const float* __restrict__ x,
                                                      const float* __restrict__ w,
                                                      const int* __restrict__ selp,
                                                      ushort_t* __restrict__ xb,
                                                      ushort_t* __restrict__ wt) {
  __shared__ ushort_t tb[128 * 128];   // 32KB
  const int bid = blockIdx.x;
  if (bid >= 1024) {
    const int i = (bid - 1024) * 256 + threadIdx.x;
    const float4* s = (const float4*)x;
    float4 a = s[i * 2], b = s[i * 2 + 1];
    uint4 o;
    o.x = f2bf2(a.x, a.y); o.y = f2bf2(a.z, a.w);
    o.z = f2bf2(b.x, b.y); o.w = f2bf2(b.z, b.w);
    ((uint4*)xb)[i] = o;
    return;
  }
  const int m = bid >> 6;
  bool used = false;
#pragma unroll
  for (int g = 0; g < B_DIM * K_SEL; ++g) used |= (read_sel(selp, g) == m);
  if (!used) return;

  const int i0 = ((bid >> 3) & 7) * 128;
  const int o0 = (bid & 7) * 128;
  const float* src = w + ((size_t)(m * IN_DIM + i0)) * OUT_DIM + o0;

  const int o4 = (threadIdx.x & 31) * 4;
  const int ib = threadIdx.x >> 5;
#pragma unroll
  for (int p = 0; p < 16; ++p) {
    const int i = ib + p * 8;
    float4 v = *(const float4*)(src + (size_t)i * OUT_DIM + o4);
    const int osw = o4 ^ (((i >> 3) & 15) << 2);
    uint2 d2; d2.x = f2bf2(v.x, v.y); d2.y = f2bf2(v.z, v.w);
    *(uint2*)(tb + i * 128 + osw) = d2;
  }
  __syncthreads();

  ushort_t* dst = wt + ((size_t)(m * OUT_DIM + o0)) * IN_DIM + i0;
  const int il = (threadIdx.x & 15) * 8;
  const int ob = threadIdx.x >> 4;
  const int q2 = ((il >> 3) & 15) << 2;
#pragma unroll
  for (int p = 0; p < 8; ++p) {
    const int o = ob + p * 16;
    const int osw = o ^ q2;
    uint4 d;
    unsigned int u[8];
#pragma unroll
    for (int j = 0; j < 8; ++j) u[j] = tb[(il + j) * 128 + osw];
    d.x = u[0] | (u[1] << 16); d.y = u[2] | (u[3] << 16);
    d.z = u[4] | (u[5] << 16); d.w = u[6] | (u[7] << 16);
    *(uint4*)(dst + (size_t)o * IN_DIM + il) = d;
  }
}

#define MFMA16 __builtin_amdgcn_mfma_f32_16x16x32_bf16

// One K-step (BK=64) of the prefetched loop. B double-buffered, A single.
//   issue B[t+1] stage -> read A-frags -> lgkm0+barrier (A consumed)
//   -> issue A[t+1] stage -> 64 MFMA w/ B-frag reads -> vmcnt0+barrier.
template<bool LAST>
__device__ __forceinline__ void gstep(
    int t, ushort_t* As,
    const ushort_t* curB0, const ushort_t* curB1,
    ushort_t* nxtB0, ushort_t* nxtB1,
    const ushort_t* Ab, const ushort_t* Bb0, const ushort_t* Bb1,
    int wv, int ardo, int brdo, int cb,
    f32x4 (&acc0)[4][4], f32x4 (&acc1)[4][4]) {
  const int k1 = (t + 1) * 64;
  if (!LAST) {
#pragma unroll
    for (int c = 0; c < 4; ++c) {
      const int j = wv * 4 + c;
      async_g2l(Bb0 + (size_t)8 * j * IN_DIM + k1, nxtB0 + j * 512);
      async_g2l(Bb1 + (size_t)8 * j * IN_DIM + k1, nxtB1 + j * 512);
    }
    __builtin_amdgcn_sched_barrier(0);
  }
  bf16x8 af0[4], af1[4];
  const ushort_t* Ard = As + ardo;
#pragma unroll
  for (int i = 0; i < 4; ++i) {
    af0[i] = *(const bf16x8*)(Ard + i * 1024 + cb);
    af1[i] = *(const bf16x8*)(Ard + i * 1024 + (cb ^ 32));
  }
  if (!LAST) {
    __builtin_amdgcn_sched_barrier(0);
    asm volatile("s_waitcnt lgkmcnt(0)" ::: "memory");
    __builtin_amdgcn_sched_barrier(0);
    __builtin_amdgcn_s_barrier();
    __builtin_amdgcn_sched_barrier(0);
#pragma unroll
    for (int c = 0; c < 4; ++c) {
      const int j = wv * 4 + c;
      async_g2l(Ab + (size_t)8 * j * (B_DIM * IN_DIM) + k1, As + j * 512);
    }
    __builtin_amdgcn_sched_barrier(0);
  }
  const ushort_t* Brd0 = curB0 + brdo;
  const ushort_t* Brd1 = curB1 + brdo;
  bf16x8 b0[4], b1[4];
#pragma unroll
  for (int n = 0; n < 4; ++n) {
    b0[n] = *(const bf16x8*)(Brd0 + n * 1024 + cb);
    b1[n] = *(const bf16x8*)(Brd1 + n * 1024 + cb);
  }
#pragma unroll
  for (int mt = 0; mt < 4; ++mt)
#pragma unroll
    for (int nt = 0; nt < 4; ++nt) {
      acc0[mt][nt] = MFMA16(af0[mt], b0[nt], acc0[mt][nt], 0, 0, 0);
      acc1[mt][nt] = MFMA16(af0[mt], b1[nt], acc1[mt][nt], 0, 0, 0);
    }
#pragma unroll
  for (int n = 0; n < 4; ++n) {
    b0[n] = *(const bf16x8*)(Brd0 + n * 1024 + (cb ^ 32));
    b1[n] = *(const bf16x8*)(Brd1 + n * 1024 + (cb ^ 32));
  }
#pragma unroll
  for (int mt = 0; mt < 4; ++mt)
#pragma unroll
    for (int nt = 0; nt < 4; ++nt) {
      acc0[mt][nt] = MFMA16(af1[mt], b0[nt], acc0[mt][nt], 0, 0, 0);
      acc1[mt][nt] = MFMA16(af1[mt], b1[nt], acc1[mt][nt], 0, 0, 0);
    }
  if (!LAST) {
    __builtin_amdgcn_sched_barrier(0);
    asm volatile("s_waitcnt vmcnt(0)" ::: "memory");
    __builtin_amdgcn_sched_barrier(0);
    __builtin_amdgcn_s_barrier();
    __builtin_amdgcn_sched_barrier(0);
  }
}

// Fused sibling GEMMs per b (both experts share the A operand). 128x128 tile,
// BK=64, 4 waves x 64x64 x 2 experts, 2 blocks/CU (80KB LDS).
// B-tiles double-buffered; A single-buffered with a consumed-barrier.
// Staging for tile t+1 issued BEFORE computing tile t -> vmcnt(0) at step end
// lands ~a full compute-phase after issue (latency hidden per-block).
__global__ __launch_bounds__(256, 2) void mlgemm_kernel(const ushort_t* __restrict__ xb,
                                                        const ushort_t* __restrict__ wt,
                                                        const int* __restrict__ selp,
                                                        const float* __restrict__ bias,
                                                        float* __restrict__ out) {
  __shared__ ushort_t As[128 * 64];         // 16KB
  __shared__ ushort_t Bs[2][2][128 * 64];   // 64KB

  const int lin = blockIdx.x;
  const int b = lin & 7;                 // XCD = lin % 8 (heuristic)
  const int mtile = (lin >> 3) & 7;
  const int ntile = lin >> 6;
  const int e0 = read_sel(selp, 2 * b);
  const int e1 = read_sel(selp, 2 * b + 1);
  const int m0 = mtile * 128;
  const int n0 = ntile * 128;

  const int lane = threadIdx.x & 63;
  const int wv = threadIdx.x >> 6;

  // staging: region j = 8 rows x 8 swizzled 16B chunks; lane l -> slot j*64+l
  const int srow = lane >> 3;
  const int sx = (((lane & 7) ^ (srow & 7)) << 3);
  const ushort_t* Ab  = xb + (size_t)(m0 + srow) * (B_DIM * IN_DIM) + b * IN_DIM + sx;
  const ushort_t* Bb0 = wt + ((size_t)(e0 * OUT_DIM + n0 + srow)) * IN_DIM + sx;
  const ushort_t* Bb1 = wt + ((size_t)(e1 * OUT_DIM + n0 + srow)) * IN_DIM + sx;

  // fragment: A[m=lane&15][k=quad*8+j]; swizzled chunk = quad ^ (row&7) ^ kk/8
  const int frow = lane & 15;
  const int quad = lane >> 4;
  const int cb = ((quad ^ (frow & 7)) << 3);
  const int wrow = (wv & 1) * 64;
  const int wcol = (wv >> 1) * 64;
  const int ardo = (wrow + frow) * 64;
  const int brdo = (wcol + frow) * 64;

  f32x4 acc0[4][4] = {};
  f32x4 acc1[4][4] = {};

  // prologue: stage tile 0 (A + both B experts)
#pragma unroll
  for (int c = 0; c < 4; ++c) {
    const int j = wv * 4 + c;
    async_g2l(Ab  + (size_t)8 * j * (B_DIM * IN_DIM), As + j * 512);
    async_g2l(Bb0 + (size_t)8 * j * IN_DIM, Bs[0][0] + j * 512);
    async_g2l(Bb1 + (size_t)8 * j * IN_DIM, Bs[0][1] + j * 512);
  }
  __builtin_amdgcn_sched_barrier(0);
  asm volatile("s_waitcnt vmcnt(0)" ::: "memory");
  __builtin_amdgcn_sched_barrier(0);
  __builtin_amdgcn_s_barrier();
  __builtin_amdgcn_sched_barrier(0);

  for (int t = 0; t < 14; t += 2) {
    gstep<false>(t,     As, Bs[0][0], Bs[0][1], Bs[1][0], Bs[1][1],
                 Ab, Bb0, Bb1, wv, ardo, brdo, cb, acc0, acc1);
    gstep<false>(t + 1, As, Bs[1][0], Bs[1][1], Bs[0][0], Bs[0][1],
                 Ab, Bb0, Bb1, wv, ardo, brdo, cb, acc0, acc1);
  }
  gstep<false>(14, As, Bs[0][0], Bs[0][1], Bs[1][0], Bs[1][1],
               Ab, Bb0, Bb1, wv, ardo, brdo, cb, acc0, acc1);
  gstep<true>(15, As, Bs[1][0], Bs[1][1], Bs[0][0], Bs[0][1],
              Ab, Bb0, Bb1, wv, ardo, brdo, cb, acc0, acc1);

  // epilogue: C/D map col=lane&15, row=quad*4+reg
  const int orow0 = m0 + wrow + quad * 4;
  const int ocol0 = n0 + wcol + frow;
  const float* bp0 = bias + (size_t)e0 * OUT_DIM;
  const float* bp1 = bias + (size_t)e1 * OUT_DIM;
  float bv0[4], bv1[4];
#pragma unroll
  for (int nt = 0; nt < 4; ++nt) {
    bv0[nt] = bp0[ocol0 + nt * 16];
    bv1[nt] = bp1[ocol0 + nt * 16];
  }
  float* C0 = out + (size_t)b * (K_SEL * OUT_DIM);
  float* C1 = C0 + OUT_DIM;
#pragma unroll
  for (int mt = 0; mt < 4; ++mt) {
#pragma unroll
    for (int r = 0; r < 4; ++r) {
      const size_t rowoff = (size_t)(orow0 + mt * 16 + r) * (B_DIM * K_SEL * OUT_DIM);
#pragma unroll
      for (int nt = 0; nt < 4; ++nt) {
        C0[rowoff + ocol0 + nt * 16] = acc0[mt][nt][r] + bv0[nt];
        C1[rowoff + ocol0 + nt * 16] = acc1[mt][nt][r] + bv1[nt];
      }
    }
  }
}

extern "C" void kernel_launch(void* const* d_in, const int* in_sizes, int n_in,
                              void* d_out, int out_size, void* d_ws, size_t ws_size,
                              hipStream_t stream) {
  const float* x    = (const float*)d_in[0];
  const int*   sel  = (const int*)d_in[1];
  const float* w    = (const float*)d_in[2];
  const float* bias = (const float*)d_in[3];
  float* out = (float*)d_out;

  ushort_t* xb = (ushort_t*)d_ws;                                   // 16 MB
  ushort_t* wt = (ushort_t*)((char*)d_ws +
                             (size_t)T_DIM * B_DIM * IN_DIM * 2);   // +32 MB

  convert_kernel<<<dim3(1024 + T_DIM * B_DIM * IN_DIM / 8 / 256), 256, 0, stream>>>(
      x, w, sel, xb, wt);
  mlgemm_kernel<<<dim3(8 * 8 * B_DIM), 256, 0, stream>>>(xb, wt, sel, bias, out);
}